// Round 9
// baseline (110.922 us; speedup 1.0000x reference)
//
#include <hip/hip_runtime.h>

// Chamfer, B=4, N=M=8192 fp32 -> scalar. Round 12: K=16 payload (2-limb split).
// r11 post-mortem: MfmaUtil 31.6% x 42.3us = 13.4us = EXACT 32x32 pipe floor -> matrix
// pipe always does minimum work; total = floor + DS + VALU + overhead, nearly summed.
// Five schedule levers were null. So shrink every term: 2-limb bf16 split needs only
// K=16 (per coord {aa',ab',ba',bb'} = 12 slots + 2x split(|p|^2)*1 + 2x 1*split(|q|^2)).
// ONE unchained v_mfma_f32_32x32x16_bf16 per 32x32 tile:
//   MFMA floor 16.6 -> 6.9 us, DS 10.2 -> 5.1 us, staging/footprint halved.
// Numerics: drops ~2^-18-rel residuals -> per-d2 err ~4e-5, final-sum err ~0.01-0.05 abs
// (~5e-5 rel). First round with absmax != 0 expected; REVERT to r9 if it fails.

#define BATCH 4
#define NPTS 8192
#define SETPTS (BATCH * NPTS)       // 32768
#define TOTPTS (2 * SETPTS)         // 65536
#define NSLOT 16                    // bf16 K-slots per point (all 16 used)
#define CHUNK_PTS 128               // col points staged per chunk = 4 tiles of 32
#define CSPLIT 8                    // col-splits per (dirb, rowblock)
#define COLS_PER (NPTS / CSPLIT)    // 1024 cols per block
#define CHUNKS_PER (COLS_PER / CHUNK_PTS)        // 8 chunks per block
#define CHUNK_BYTES (CHUNK_PTS * NSLOT * 2)      // 4096
#define DEPTH 3                     // ring-buffer depth (12 KB LDS)
#define RT 2                        // 32-row tiles per wave (64 rows/wave)
#define ROWS_BLK (4 * RT * 32)      // 256 rows per block
#define RBLK (NPTS / ROWS_BLK)      // 32 row-blocks

typedef __attribute__((ext_vector_type(8))) short bf16x8;
typedef __attribute__((ext_vector_type(16))) float f32x16;

__device__ __forceinline__ float bf16rn(float v) {  // round-to-nearest-even to bf16 value
  unsigned u = __float_as_uint(v);
  u = (u + 0x7FFFu + ((u >> 16) & 1u)) & 0xFFFF0000u;
  return __uint_as_float(u);
}
__device__ __forceinline__ unsigned short b2u(float v) {  // bf16 bits of a bf16-valued f32
  return (unsigned short)(__float_as_uint(v) >> 16);
}

// Per point (16 slots): s-vec (row role, carries -2) and t-vec (col role):
//   coord d (limbs a,b): s[4d+]: [-2a,-2a,-2b,-2b]   t[4d+]: [a,b,a,b]
//     -> all four limb products a*a', a*b', b*a', b*b' of -2 x_P x_Q
//   slots 12-13: s = split(|p|^2) = (g,h), t = (1,1)
//   slots 14-15: s = (1,1), t = split(|q|^2)
__global__ __launch_bounds__(256) void chamfer_prep_kernel(
    const float* __restrict__ p1, const float* __restrict__ p2,
    unsigned short* __restrict__ sArr, unsigned short* __restrict__ tArr,
    unsigned int* __restrict__ wmin, float* __restrict__ out) {
  const int i = blockIdx.x * 256 + threadIdx.x;  // 0..65535
  const float* src = (i < SETPTS) ? (p1 + 3 * (size_t)i) : (p2 + 3 * (size_t)(i - SETPTS));
  const float co[3] = {src[0], src[1], src[2]};
  union { unsigned short u[16]; uint4 v[2]; } sv, tv;
#pragma unroll
  for (int d = 0; d < 3; ++d) {
    const float v = co[d];
    const float a = bf16rn(v);
    const float bb = bf16rn(v - a);     // Sterbenz-exact residual, then rounded
    const unsigned short as = b2u(-2.f * a), bs = b2u(-2.f * bb);
    const unsigned short at = b2u(a), bt = b2u(bb);
    sv.u[4 * d + 0] = as; sv.u[4 * d + 1] = as;
    sv.u[4 * d + 2] = bs; sv.u[4 * d + 3] = bs;
    tv.u[4 * d + 0] = at; tv.u[4 * d + 1] = bt;
    tv.u[4 * d + 2] = at; tv.u[4 * d + 3] = bt;
  }
  const float sp = fmaf(co[0], co[0], fmaf(co[1], co[1], co[2] * co[2]));
  const float g = bf16rn(sp);
  const float h = bf16rn(sp - g);
  sv.u[12] = b2u(g); sv.u[13] = b2u(h);
  tv.u[12] = 0x3F80; tv.u[13] = 0x3F80;  // bf16(1.0)
  sv.u[14] = 0x3F80; sv.u[15] = 0x3F80;
  tv.u[14] = b2u(g); tv.u[15] = b2u(h);
  uint4* sd = (uint4*)(sArr + (size_t)i * NSLOT);
  uint4* td = (uint4*)(tArr + (size_t)i * NSLOT);
  sd[0] = sv.v[0]; sd[1] = sv.v[1];
  td[0] = tv.v[0]; td[1] = tv.v[1];
  wmin[i] = 0x7F800000u;  // +inf bits: > any clamped finite float's bits
  if (i == 0) out[0] = 0.f;
}

// Block: 4 waves x 2 row-tiles(32) = 256 rows, 8 chunks (1024 cols) of its col-split.
// LDS chunk layout (pre-permuted global source, m173): 16B slot s within chunk holds
// (jt = s>>6, half = (s>>5)&1, col = s&31); reader's slot index for a tile is exactly
// `lane` (kh*32 + l31), so ds_read_b128 at lane*16 is linear/conflict-free AND is the
// 32x32x16 B-fragment (col = lane&31, k-group = (lane>>5)*8).
__global__ __launch_bounds__(256, 6) void chamfer_mfma_kernel(
    const unsigned short* __restrict__ sArr, const unsigned short* __restrict__ tArr,
    unsigned int* __restrict__ wmin) {
  const int bx = blockIdx.x;
  const int dirb = bx & 7;         // bx%8 -> XCD-aligned: per-XCD L2 sees one dirb's t-set
  const int rblk = (bx >> 3) & (RBLK - 1);  // 0..31 (256 rows each)
  const int csp = bx >> 8;         // 0..7 (1024 cols each)
  const int dir = dirb >> 2, b = dirb & 3;
  const unsigned short* sb = sArr + (size_t)((dir ? SETPTS : 0) + b * NPTS) * NSLOT;
  const unsigned short* tb = tArr + (size_t)((dir ? 0 : SETPTS) + b * NPTS) * NSLOT;
  unsigned int* wm = wmin + (size_t)dirb * NPTS;

  const int t = threadIdx.x;
  const int lane = t & 63, wid = t >> 6;
  const int l31 = lane & 31, kh = lane >> 5;  // col/row in tile, k-group

  __shared__ uint4 sbuf[DEPTH][CHUNK_BYTES / 16];  // 3 x 4 KB ring
  char* cs = (char*)sbuf;

  const int rowbase = rblk * ROWS_BLK + wid * (RT * 32);  // wave owns 64 rows = 2 tiles
  bf16x8 a[RT];  // A-fragment: row = lane&31, k = (lane>>5)*8 + [0..7]
#pragma unroll
  for (int m = 0; m < RT; ++m)
    a[m] = *(const bf16x8*)(sb + (size_t)(rowbase + m * 32 + l31) * NSLOT + kh * 8);

  const char* gsrc;
  {
    const int jt = t >> 6, half = (t >> 5) & 1, col = t & 31;
    gsrc = (const char*)(tb + (size_t)(csp * COLS_PER + jt * 32 + col) * NSLOT + half * 8);
  }

  auto stage = [&](int chunk, int buf) {  // 1 global_load_lds (16B) per thread
    __builtin_amdgcn_global_load_lds(
        (const __attribute__((address_space(1))) void*)(gsrc + (size_t)chunk * CHUNK_BYTES),
        (__attribute__((address_space(3))) void*)(cs + buf * CHUNK_BYTES + t * 16), 16, 0, 0);
  };

  f32x16 acc[RT];
#pragma unroll
  for (int m = 0; m < RT; ++m)
#pragma unroll
    for (int r = 0; r < 16; ++r) acc[m][r] = INFINITY;
  const f32x16 zero = {0.f, 0.f, 0.f, 0.f, 0.f, 0.f, 0.f, 0.f,
                       0.f, 0.f, 0.f, 0.f, 0.f, 0.f, 0.f, 0.f};

  stage(0, 0);  // prologue: chunks 0,1 in flight (2 loads/thread)
  stage(1, 1);

  int cbuf = 0, ibuf = 2;
  for (int c = 0; c < CHUNKS_PER; ++c) {
    // T4: counted wait -- own chunk-c load done, chunk c+1's load stays in flight.
    if (c + 1 < CHUNKS_PER) asm volatile("s_waitcnt vmcnt(1)" ::: "memory");
    else                    asm volatile("s_waitcnt vmcnt(0)" ::: "memory");
    __builtin_amdgcn_s_barrier();        // all waves' chunk-c loads landed; readers of
    __builtin_amdgcn_sched_barrier(0);   //  chunk c-1 all done
    if (c + 2 < CHUNKS_PER) {            // stage into the buffer chunk c-1 vacated
      stage(c + 2, ibuf);
      ibuf = (ibuf == DEPTH - 1) ? 0 : ibuf + 1;
    }
    const char* bbase = cs + cbuf * CHUNK_BYTES + lane * 16;
    __builtin_amdgcn_s_setprio(1);       // T5: favor the MFMA cluster
#pragma unroll
    for (int jt = 0; jt < 4; jt += 2) {  // 32-col tile PAIRS: min3 folds two results/op
      const bf16x8 bA = *(const bf16x8*)(bbase + jt * 1024);        // linear ds_read_b128
      const bf16x8 bB = *(const bf16x8*)(bbase + (jt + 1) * 1024);
#pragma unroll
      for (int m = 0; m < RT; ++m) {
        const f32x16 dA = __builtin_amdgcn_mfma_f32_32x32x16_bf16(a[m], bA, zero, 0, 0, 0);
        const f32x16 dB = __builtin_amdgcn_mfma_f32_32x32x16_bf16(a[m], bB, zero, 0, 0, 0);
#pragma unroll
        for (int r = 0; r < 16; ++r)
          acc[m][r] = fminf(fminf(acc[m][r], dA[r]), dB[r]);  // v_min3_f32
      }
    }
    __builtin_amdgcn_s_setprio(0);
    cbuf = (cbuf == DEPTH - 1) ? 0 : cbuf + 1;
  }

  // fold the 32 col-lanes (xor masks 1..16 keep bit5 = kh) -> row-mins
#pragma unroll
  for (int mk = 1; mk <= 16; mk <<= 1) {
#pragma unroll
    for (int m = 0; m < RT; ++m)
#pragma unroll
      for (int r = 0; r < 16; ++r)
        acc[m][r] = fminf(acc[m][r], __shfl_xor(acc[m][r], mk, 64));
  }
  if (l31 == 0) {  // C/D: col=lane&31, row=(reg&3)+8*(reg>>2)+4*(lane>>5) [m74/m101]
#pragma unroll
    for (int m = 0; m < RT; ++m)
#pragma unroll
      for (int r = 0; r < 16; ++r) {
        const int row = rowbase + m * 32 + (r & 3) + 8 * (r >> 2) + 4 * kh;
        atomicMin(&wm[row], __float_as_uint(fmaxf(acc[m][r], 0.f)));
      }
  }
}

__global__ __launch_bounds__(256) void chamfer_reduce_kernel(const unsigned int* __restrict__ wmin,
                                                             float* __restrict__ out) {
  // 65536 elements; 64 blocks x 256 threads x 4 elems
  float s = 0.f;
  const int base = blockIdx.x * 1024 + threadIdx.x;
#pragma unroll
  for (int k = 0; k < 4; ++k) s += __uint_as_float(wmin[base + k * 256]);
#pragma unroll
  for (int off = 32; off > 0; off >>= 1) s += __shfl_down(s, off, 64);
  __shared__ float wsum[4];
  const int lane = threadIdx.x & 63, wid = threadIdx.x >> 6;
  if (lane == 0) wsum[wid] = s;
  __syncthreads();
  if (threadIdx.x == 0) atomicAdd(out, wsum[0] + wsum[1] + wsum[2] + wsum[3]);
}

extern "C" void kernel_launch(void* const* d_in, const int* in_sizes, int n_in,
                              void* d_out, int out_size, void* d_ws, size_t ws_size,
                              hipStream_t stream) {
  const float* p1 = (const float*)d_in[0];
  const float* p2 = (const float*)d_in[1];
  float* out = (float*)d_out;
  unsigned short* sArr = (unsigned short*)d_ws;                       // 2 MB
  unsigned short* tArr = (unsigned short*)((char*)d_ws + (2 << 20));  // 2 MB
  unsigned int* wmin = (unsigned int*)((char*)d_ws + (4 << 20));      // 256 KB

  chamfer_prep_kernel<<<dim3(TOTPTS / 256), dim3(256), 0, stream>>>(p1, p2, sArr, tArr, wmin, out);
  chamfer_mfma_kernel<<<dim3(8 * RBLK * CSPLIT), dim3(256), 0, stream>>>(sArr, tArr, wmin);
  chamfer_reduce_kernel<<<dim3(64), dim3(256), 0, stream>>>(wmin, out);
}